// Round 1
// baseline (481.527 us; speedup 1.0000x reference)
//
#include <hip/hip_runtime.h>

#define D_FEAT 64

// Zero output + degree scratch (atomics accumulate, so every launch must re-init).
__global__ void zero_kernel(float* __restrict__ out, long long n_out,
                            int* __restrict__ deg, int n_deg) {
    long long i = (long long)blockIdx.x * blockDim.x + threadIdx.x;
    long long stride = (long long)gridDim.x * blockDim.x;
    for (long long j = i; j < n_out; j += stride) out[j] = 0.0f;
    for (long long j = i; j < n_deg; j += stride) deg[j] = 0;
}

// Integer degree counts (exact, order-independent).
__global__ void degree_kernel(const int* __restrict__ src, const int* __restrict__ dst,
                              int n_edges, int* __restrict__ outdeg, int* __restrict__ indeg) {
    int i = blockIdx.x * blockDim.x + threadIdx.x;
    int stride = gridDim.x * blockDim.x;
    for (int e = i; e < n_edges; e += stride) {
        atomicAdd(&outdeg[src[e]], 1);
        atomicAdd(&indeg[dst[e]], 1);
    }
}

// One 64-lane group per edge: lane d handles feature d.
// out[dst] += emb[src] * rsqrt(max(outdeg[src],1))
__global__ void scatter_kernel(const float* __restrict__ emb,
                               const int* __restrict__ src, const int* __restrict__ dst,
                               const int* __restrict__ outdeg,
                               float* __restrict__ out, int n_edges) {
    const int edges_per_block = blockDim.x >> 6;          // 64 lanes per edge
    const int d = threadIdx.x & 63;
    long long e0 = (long long)blockIdx.x * edges_per_block + (threadIdx.x >> 6);
    long long estride = (long long)gridDim.x * edges_per_block;
    for (long long e = e0; e < n_edges; e += estride) {
        int s = src[e];
        int t = dst[e];
        int od = outdeg[s];
        float scale = rsqrtf((float)(od > 1 ? od : 1));
        float v = emb[(long long)s * D_FEAT + d] * scale;
        atomicAdd(&out[(long long)t * D_FEAT + d], v);
    }
}

// out[i,:] *= rsqrt(max(indeg[i],1))
__global__ void scale_kernel(float* __restrict__ out, const int* __restrict__ indeg,
                             long long n_elems) {
    long long i = (long long)blockIdx.x * blockDim.x + threadIdx.x;
    long long stride = (long long)gridDim.x * blockDim.x;
    for (long long j = i; j < n_elems; j += stride) {
        int node = (int)(j >> 6);
        int id = indeg[node];
        out[j] *= rsqrtf((float)(id > 1 ? id : 1));
    }
}

extern "C" void kernel_launch(void* const* d_in, const int* in_sizes, int n_in,
                              void* d_out, int out_size, void* d_ws, size_t ws_size,
                              hipStream_t stream) {
    const float* emb = (const float*)d_in[0];
    const int* src = (const int*)d_in[1];
    const int* dst = (const int*)d_in[2];
    // d_in[3] is n_nodes scalar on device; derive sizes host-side instead.
    const int n_nodes = in_sizes[0] / D_FEAT;
    const int n_edges = in_sizes[1];
    const long long n_out = (long long)n_nodes * D_FEAT;

    float* out = (float*)d_out;
    int* outdeg = (int*)d_ws;                 // n_nodes ints
    int* indeg = outdeg + n_nodes;            // n_nodes ints

    const int block = 256;

    // 1) zero out + degrees
    {
        int grid = 2048;
        zero_kernel<<<grid, block, 0, stream>>>(out, n_out, outdeg, 2 * n_nodes);
    }
    // 2) degrees
    {
        int grid = 2048;
        degree_kernel<<<grid, block, 0, stream>>>(src, dst, n_edges, outdeg, indeg);
    }
    // 3) scatter-add
    {
        int grid = 2048;  // grid-stride, 4 edges per 256-thread block per iter
        scatter_kernel<<<grid, block, 0, stream>>>(emb, src, dst, outdeg, out, n_edges);
    }
    // 4) post-scale
    {
        int grid = 2048;
        scale_kernel<<<grid, block, 0, stream>>>(out, indeg, n_out);
    }
}

// Round 2
// 328.183 us; speedup vs baseline: 1.4673x; 1.4673x over previous
//
#include <hip/hip_runtime.h>

#define D_FEAT 64

// ---------- counting-sort pipeline ----------

__global__ void zero_ints(int* __restrict__ p, int n) {
    int i = blockIdx.x * blockDim.x + threadIdx.x;
    int stride = gridDim.x * blockDim.x;
    for (int j = i; j < n; j += stride) p[j] = 0;
}

// hist_in[dst]++ , hist_out[src]++
__global__ void histogram_kernel(const int* __restrict__ src, const int* __restrict__ dst,
                                 int n_edges, int* __restrict__ hist_out, int* __restrict__ hist_in) {
    int i = blockIdx.x * blockDim.x + threadIdx.x;
    int stride = gridDim.x * blockDim.x;
    for (int e = i; e < n_edges; e += stride) {
        atomicAdd(&hist_out[src[e]], 1);
        atomicAdd(&hist_in[dst[e]], 1);
    }
}

// Block-local exclusive scan of hist -> excl, per-block totals -> bsum
__global__ void scan_a(const int* __restrict__ hist, int n,
                       int* __restrict__ excl, int* __restrict__ bsum) {
    __shared__ int s[256];
    int t = threadIdx.x;
    int i = blockIdx.x * 256 + t;
    int v = (i < n) ? hist[i] : 0;
    s[t] = v;
    __syncthreads();
    for (int off = 1; off < 256; off <<= 1) {
        int x = (t >= off) ? s[t - off] : 0;
        __syncthreads();
        if (t >= off) s[t] += x;
        __syncthreads();
    }
    if (i < n) excl[i] = s[t] - v;
    if (t == 255) bsum[blockIdx.x] = s[255];
}

// Single-block exclusive scan of bsum (in place). nblk <= 1024.
__global__ void scan_b(int* __restrict__ bsum, int nblk) {
    __shared__ int s[1024];
    int t = threadIdx.x;
    int v = (t < nblk) ? bsum[t] : 0;
    s[t] = v;
    __syncthreads();
    for (int off = 1; off < 1024; off <<= 1) {
        int x = (t >= off) ? s[t - off] : 0;
        __syncthreads();
        if (t >= off) s[t] += x;
        __syncthreads();
    }
    if (t < nblk) bsum[t] = s[t] - v;
}

// starts[i] += bsum[i/256]; cursor[i] = starts[i]; starts[n] = n_edges
__global__ void scan_c(int* __restrict__ starts, int* __restrict__ cursor,
                       const int* __restrict__ bsum, int n, int n_edges) {
    int i = blockIdx.x * blockDim.x + threadIdx.x;
    if (i < n) {
        int v = starts[i] + bsum[i >> 8];
        starts[i] = v;
        cursor[i] = v;
    }
    if (i == 0) starts[n] = n_edges;
}

// sorted_src[pos] = src[e], pos = cursor[dst[e]]++
__global__ void bucket_scatter(const int* __restrict__ src, const int* __restrict__ dst,
                               int n_edges, int* __restrict__ cursor,
                               int* __restrict__ sorted_src) {
    int i = blockIdx.x * blockDim.x + threadIdx.x;
    int stride = gridDim.x * blockDim.x;
    for (int e = i; e < n_edges; e += stride) {
        int pos = atomicAdd(&cursor[dst[e]], 1);
        sorted_src[pos] = src[e];
    }
}

// One 64-lane wave per node; lane d = feature d. 4-way unrolled gather loop.
__global__ void aggregate_kernel(const float* __restrict__ emb,
                                 const int* __restrict__ sorted_src,
                                 const int* __restrict__ starts,
                                 const int* __restrict__ outdeg,
                                 float* __restrict__ out, int n_nodes) {
    int node = blockIdx.x * (blockDim.x >> 6) + (threadIdx.x >> 6);
    if (node >= n_nodes) return;
    int d = threadIdx.x & 63;
    int e = starts[node];
    int e_end = starts[node + 1];
    int indeg = e_end - e;
    float a0 = 0.f, a1 = 0.f, a2 = 0.f, a3 = 0.f;
    for (; e + 4 <= e_end; e += 4) {
        int i0 = sorted_src[e], i1 = sorted_src[e + 1];
        int i2 = sorted_src[e + 2], i3 = sorted_src[e + 3];
        int o0 = outdeg[i0], o1 = outdeg[i1], o2 = outdeg[i2], o3 = outdeg[i3];
        a0 += emb[(long long)i0 * D_FEAT + d] * rsqrtf((float)(o0 > 1 ? o0 : 1));
        a1 += emb[(long long)i1 * D_FEAT + d] * rsqrtf((float)(o1 > 1 ? o1 : 1));
        a2 += emb[(long long)i2 * D_FEAT + d] * rsqrtf((float)(o2 > 1 ? o2 : 1));
        a3 += emb[(long long)i3 * D_FEAT + d] * rsqrtf((float)(o3 > 1 ? o3 : 1));
    }
    for (; e < e_end; ++e) {
        int i0 = sorted_src[e];
        int o0 = outdeg[i0];
        a0 += emb[(long long)i0 * D_FEAT + d] * rsqrtf((float)(o0 > 1 ? o0 : 1));
    }
    float acc = (a0 + a1) + (a2 + a3);
    out[(long long)node * D_FEAT + d] = acc * rsqrtf((float)(indeg > 1 ? indeg : 1));
}

// ---------- fallback (atomic path) if workspace is too small ----------

__global__ void fb_zero(float* __restrict__ out, long long n_out,
                        int* __restrict__ deg, int n_deg) {
    long long i = (long long)blockIdx.x * blockDim.x + threadIdx.x;
    long long stride = (long long)gridDim.x * blockDim.x;
    for (long long j = i; j < n_out; j += stride) out[j] = 0.0f;
    for (long long j = i; j < n_deg; j += stride) deg[j] = 0;
}

__global__ void fb_scatter(const float* __restrict__ emb,
                           const int* __restrict__ src, const int* __restrict__ dst,
                           const int* __restrict__ outdeg,
                           float* __restrict__ out, int n_edges) {
    const int epb = blockDim.x >> 6;
    const int d = threadIdx.x & 63;
    long long e0 = (long long)blockIdx.x * epb + (threadIdx.x >> 6);
    long long estride = (long long)gridDim.x * epb;
    for (long long e = e0; e < n_edges; e += estride) {
        int s = src[e];
        int t = dst[e];
        int od = outdeg[s];
        float v = emb[(long long)s * D_FEAT + d] * rsqrtf((float)(od > 1 ? od : 1));
        atomicAdd(&out[(long long)t * D_FEAT + d], v);
    }
}

__global__ void fb_scale(float* __restrict__ out, const int* __restrict__ indeg,
                         long long n_elems) {
    long long i = (long long)blockIdx.x * blockDim.x + threadIdx.x;
    long long stride = (long long)gridDim.x * blockDim.x;
    for (long long j = i; j < n_elems; j += stride) {
        int id = indeg[(int)(j >> 6)];
        out[j] *= rsqrtf((float)(id > 1 ? id : 1));
    }
}

extern "C" void kernel_launch(void* const* d_in, const int* in_sizes, int n_in,
                              void* d_out, int out_size, void* d_ws, size_t ws_size,
                              hipStream_t stream) {
    const float* emb = (const float*)d_in[0];
    const int* src = (const int*)d_in[1];
    const int* dst = (const int*)d_in[2];
    const int n_nodes = in_sizes[0] / D_FEAT;
    const int n_edges = in_sizes[1];
    float* out = (float*)d_out;
    const int block = 256;

    // workspace layout (ints)
    size_t need = ((size_t)n_nodes * 4 + 1 + 1024 + (size_t)n_edges) * sizeof(int);
    if (ws_size >= need) {
        int* hist_in = (int*)d_ws;                 // n
        int* hist_out = hist_in + n_nodes;         // n
        int* starts = hist_out + n_nodes;          // n+1
        int* cursor = starts + n_nodes + 1;        // n
        int* bsum = cursor + n_nodes;              // 1024
        int* sorted_src = bsum + 1024;             // E

        int nblk_scan = (n_nodes + 255) / 256;     // 391 for 100K

        zero_ints<<<1024, block, 0, stream>>>(hist_in, 2 * n_nodes);
        histogram_kernel<<<2048, block, 0, stream>>>(src, dst, n_edges, hist_out, hist_in);
        scan_a<<<nblk_scan, 256, 0, stream>>>(hist_in, n_nodes, starts, bsum);
        scan_b<<<1, 1024, 0, stream>>>(bsum, nblk_scan);
        scan_c<<<nblk_scan, 256, 0, stream>>>(starts, cursor, bsum, n_nodes, n_edges);
        bucket_scatter<<<2048, block, 0, stream>>>(src, dst, n_edges, cursor, sorted_src);
        int agg_blocks = (n_nodes + 3) / 4;        // 4 nodes (waves) per 256-thread block
        aggregate_kernel<<<agg_blocks, block, 0, stream>>>(emb, sorted_src, starts,
                                                           hist_out, out, n_nodes);
    } else {
        // fallback: atomic scatter path
        int* outdeg = (int*)d_ws;
        int* indeg = outdeg + n_nodes;
        long long n_out = (long long)n_nodes * D_FEAT;
        fb_zero<<<2048, block, 0, stream>>>(out, n_out, outdeg, 2 * n_nodes);
        histogram_kernel<<<2048, block, 0, stream>>>(src, dst, n_edges, outdeg, indeg);
        fb_scatter<<<2048, block, 0, stream>>>(emb, src, dst, outdeg, out, n_edges);
        fb_scale<<<2048, block, 0, stream>>>(out, indeg, n_out);
    }
}